// Round 1
// baseline (12260.910 us; speedup 1.0000x reference)
//
#include <hip/hip_runtime.h>

#define N_NODES 100000
#define R_REL   8
#define E_EDGES 800000
#define D_FEAT  128
#define B_BASES 4

// weight[r][i][o] = sum_b w_comp[r][b] * bases[b][i][o]
__global__ __launch_bounds__(256) void compute_weight_kernel(
    const float* __restrict__ w_comp,
    const float* __restrict__ bases,
    float* __restrict__ weight) {
    int idx = blockIdx.x * 256 + threadIdx.x;            // over R*D*D
    if (idx >= R_REL * D_FEAT * D_FEAT) return;
    int r  = idx / (D_FEAT * D_FEAT);
    int io = idx % (D_FEAT * D_FEAT);
    float acc = 0.f;
#pragma unroll
    for (int b = 0; b < B_BASES; ++b)
        acc = fmaf(w_comp[r * B_BASES + b], bases[b * D_FEAT * D_FEAT + io], acc);
    weight[idx] = acc;
}

// One relation: msg[dst] += x[src], deg[dst] += 1.  32 lanes per edge.
__global__ __launch_bounds__(256) void scatter_kernel(
    const float* __restrict__ x,
    const int*   __restrict__ src,
    const int*   __restrict__ dst,
    float* __restrict__ msg,
    float* __restrict__ deg) {
    int t  = blockIdx.x * 256 + threadIdx.x;
    int e  = t >> 5;
    int f4 = (t & 31) << 2;
    if (e >= E_EDGES) return;
    int s = src[e];
    int d = dst[e];
    const float4 v = *(const float4*)(x + (size_t)s * D_FEAT + f4);
    float* mp = msg + (size_t)d * D_FEAT + f4;
    atomicAdd(mp + 0, v.x);
    atomicAdd(mp + 1, v.y);
    atomicAdd(mp + 2, v.z);
    atomicAdd(mp + 3, v.w);
    if ((t & 31) == 0) atomicAdd(deg + d, 1.0f);
}

// C = maybe_relu( rowscale(A) @ W + addsrc + bias )   (or C += ... when accum)
// A: [M,128] row-major, W: [128,128] row-major. Block = 256 threads, 64 rows.
// Thread (cg = tid&31, rg = tid>>5) computes rows rg*8..rg*8+7, cols cg*4..cg*4+3.
__global__ __launch_bounds__(256) void gemm128_kernel(
    const float* __restrict__ A,
    const float* __restrict__ W,
    const float* __restrict__ deg,      // nullable: row scale 1/max(deg,1)
    const float* __restrict__ addsrc,   // nullable
    const float* __restrict__ bias,     // nullable
    float* __restrict__ C,
    int M, int do_relu, int accum) {
    const int tid  = threadIdx.x;
    const int cg   = tid & 31;
    const int rg   = tid >> 5;
    const int col  = cg << 2;
    const int row0 = blockIdx.x * 64 + rg * 8;

    float4 acc[8];
#pragma unroll
    for (int i = 0; i < 8; ++i) acc[i] = make_float4(0.f, 0.f, 0.f, 0.f);

    const float* arow[8];
#pragma unroll
    for (int i = 0; i < 8; ++i) {
        int m = row0 + i;
        int mc = m < M ? m : M - 1;   // clamp for safe loads; store is guarded
        arow[i] = A + (size_t)mc * D_FEAT;
    }

    for (int k0 = 0; k0 < D_FEAT; k0 += 4) {
        float4 w0 = *(const float4*)(W + (k0 + 0) * D_FEAT + col);
        float4 w1 = *(const float4*)(W + (k0 + 1) * D_FEAT + col);
        float4 w2 = *(const float4*)(W + (k0 + 2) * D_FEAT + col);
        float4 w3 = *(const float4*)(W + (k0 + 3) * D_FEAT + col);
#pragma unroll
        for (int i = 0; i < 8; ++i) {
            float4 a = *(const float4*)(arow[i] + k0);
            acc[i].x = fmaf(a.x, w0.x, fmaf(a.y, w1.x, fmaf(a.z, w2.x, fmaf(a.w, w3.x, acc[i].x))));
            acc[i].y = fmaf(a.x, w0.y, fmaf(a.y, w1.y, fmaf(a.z, w2.y, fmaf(a.w, w3.y, acc[i].y))));
            acc[i].z = fmaf(a.x, w0.z, fmaf(a.y, w1.z, fmaf(a.z, w2.z, fmaf(a.w, w3.z, acc[i].z))));
            acc[i].w = fmaf(a.x, w0.w, fmaf(a.y, w1.w, fmaf(a.z, w2.w, fmaf(a.w, w3.w, acc[i].w))));
        }
    }

#pragma unroll
    for (int i = 0; i < 8; ++i) {
        int m = row0 + i;
        if (m < M) {
            float4 v = acc[i];
            if (deg) {
                float inv = 1.0f / fmaxf(deg[m], 1.0f);
                v.x *= inv; v.y *= inv; v.z *= inv; v.w *= inv;
            }
            if (addsrc) {
                float4 ad = *(const float4*)(addsrc + (size_t)m * D_FEAT + col);
                v.x += ad.x; v.y += ad.y; v.z += ad.z; v.w += ad.w;
            }
            if (bias) {
                float4 bs = *(const float4*)(bias + col);
                v.x += bs.x; v.y += bs.y; v.z += bs.z; v.w += bs.w;
            }
            if (accum) {
                float4 c = *(const float4*)(C + (size_t)m * D_FEAT + col);
                v.x += c.x; v.y += c.y; v.z += c.z; v.w += c.w;
            }
            if (do_relu) {
                v.x = fmaxf(v.x, 0.f); v.y = fmaxf(v.y, 0.f);
                v.z = fmaxf(v.z, 0.f); v.w = fmaxf(v.w, 0.f);
            }
            *(float4*)(C + (size_t)m * D_FEAT + col) = v;
        }
    }
}

extern "C" void kernel_launch(void* const* d_in, const int* in_sizes, int n_in,
                              void* d_out, int out_size, void* d_ws, size_t ws_size,
                              hipStream_t stream) {
    const float* x           = (const float*)d_in[0];
    const int*   edge_src    = (const int*)d_in[1];
    const int*   edge_dst    = (const int*)d_in[2];
    const float* w_comp      = (const float*)d_in[3];
    const float* bases       = (const float*)d_in[4];
    const float* loop_weight = (const float*)d_in[5];
    const float* h_bias      = (const float*)d_in[6];
    const float* ngnn_w      = (const float*)d_in[7];
    float* out = (float*)d_out;

    // workspace layout
    char* ws = (char*)d_ws;
    const size_t WEIGHT_BYTES = (size_t)R_REL * D_FEAT * D_FEAT * 4;   // 512 KB
    const size_t MAT_BYTES    = (size_t)N_NODES * D_FEAT * 4;          // 51.2 MB
    const size_t DEG_BYTES    = (size_t)N_NODES * 4;                   // 400 KB
    float* weight = (float*)ws;                                        // [8][128][128]
    float* msg    = (float*)(ws + WEIGHT_BYTES);                       // [N][128] (later reused as h2)
    float* deg    = (float*)(ws + WEIGHT_BYTES + MAT_BYTES);           // [N]
    float* h      = (float*)(ws + WEIGHT_BYTES + MAT_BYTES + DEG_BYTES); // [N][128] (later reused as h3)

    const int GEMM_GRID = (N_NODES + 63) / 64;   // 1563

    // 0) basis-combined weights
    compute_weight_kernel<<<(R_REL * D_FEAT * D_FEAT + 255) / 256, 256, 0, stream>>>(
        w_comp, bases, weight);

    // h accumulator = 0
    hipMemsetAsync(h, 0, MAT_BYTES, stream);

    // 1) per-relation: scatter-aggregate then h += (msg/deg) @ weight[r]
    for (int r = 0; r < R_REL; ++r) {
        hipMemsetAsync(msg, 0, MAT_BYTES, stream);
        hipMemsetAsync(deg, 0, DEG_BYTES, stream);
        scatter_kernel<<<(E_EDGES * 32) / 256, 256, 0, stream>>>(
            x, edge_src + (size_t)r * E_EDGES, edge_dst + (size_t)r * E_EDGES, msg, deg);
        gemm128_kernel<<<GEMM_GRID, 256, 0, stream>>>(
            msg, weight + (size_t)r * D_FEAT * D_FEAT, deg,
            nullptr, nullptr, h, N_NODES, /*relu=*/0, /*accum=*/1);
    }

    // 2) h2 = relu(x @ loop_weight + h + bias)   (h2 stored in msg buffer)
    gemm128_kernel<<<GEMM_GRID, 256, 0, stream>>>(
        x, loop_weight, nullptr, h, h_bias, msg, N_NODES, /*relu=*/1, /*accum=*/0);

    // 3) h3 = relu(h2 @ ngnn_w[0])   (h3 stored in h buffer)
    gemm128_kernel<<<GEMM_GRID, 256, 0, stream>>>(
        msg, ngnn_w, nullptr, nullptr, nullptr, h, N_NODES, /*relu=*/1, /*accum=*/0);

    // 4) out = relu(h3 @ ngnn_w[1])
    gemm128_kernel<<<GEMM_GRID, 256, 0, stream>>>(
        h, ngnn_w + D_FEAT * D_FEAT, nullptr, nullptr, nullptr, out, N_NODES, /*relu=*/1, /*accum=*/0);
}

// Round 2
// 2230.422 us; speedup vs baseline: 5.4971x; 5.4971x over previous
//
#include <hip/hip_runtime.h>

#define N_NODES 100000
#define R_REL   8
#define E_EDGES 800000
#define D_FEAT  128
#define B_BASES 4
#define RN      (R_REL * N_NODES)          // 800000 segments
#define RE      (R_REL * E_EDGES)          // 6.4M edges
#define SCAN_BS 1024                       // elements per scan block
#define SCAN_NB ((RN + SCAN_BS - 1) / SCAN_BS)   // 782

// weight[r][i][o] = sum_b w_comp[r][b] * bases[b][i][o]
__global__ __launch_bounds__(256) void compute_weight_kernel(
    const float* __restrict__ w_comp,
    const float* __restrict__ bases,
    float* __restrict__ weight) {
    int idx = blockIdx.x * 256 + threadIdx.x;
    if (idx >= R_REL * D_FEAT * D_FEAT) return;
    int r  = idx / (D_FEAT * D_FEAT);
    int io = idx % (D_FEAT * D_FEAT);
    float acc = 0.f;
#pragma unroll
    for (int b = 0; b < B_BASES; ++b)
        acc = fmaf(w_comp[r * B_BASES + b], bases[b * D_FEAT * D_FEAT + io], acc);
    weight[idx] = acc;
}

// ---- CSR build ----------------------------------------------------------

// deg[r*N + dst]++ over all R*E edges (int atomics on 3.2 MB L2-resident array)
__global__ __launch_bounds__(256) void count_kernel(
    const int* __restrict__ dst, int* __restrict__ deg) {
    int e = blockIdx.x * 256 + threadIdx.x;
    if (e >= RE) return;
    int r = e / E_EDGES;
    atomicAdd(&deg[r * N_NODES + dst[e]], 1);
}

// block-level exclusive scan: 1024 elems/block (256 thr x 4), partial + block sums
__global__ __launch_bounds__(256) void scan1_kernel(
    const int* __restrict__ deg, int* __restrict__ part, int* __restrict__ bsums) {
    __shared__ int lds[256];
    int t = threadIdx.x;
    int base = blockIdx.x * SCAN_BS + t * 4;
    int v0 = base + 0 < RN ? deg[base + 0] : 0;
    int v1 = base + 1 < RN ? deg[base + 1] : 0;
    int v2 = base + 2 < RN ? deg[base + 2] : 0;
    int v3 = base + 3 < RN ? deg[base + 3] : 0;
    int s0 = v0, s1 = s0 + v1, s2 = s1 + v2, s3 = s2 + v3;   // thread-local inclusive
    lds[t] = s3;
    __syncthreads();
    int val = s3;
    for (int off = 1; off < 256; off <<= 1) {
        int y = (t >= off) ? lds[t - off] : 0;
        __syncthreads();
        val += y;
        lds[t] = val;
        __syncthreads();
    }
    int excl = val - s3;     // exclusive prefix of this thread's chunk within block
    if (base + 0 < RN) part[base + 0] = excl;
    if (base + 1 < RN) part[base + 1] = excl + s0;
    if (base + 2 < RN) part[base + 2] = excl + s1;
    if (base + 3 < RN) part[base + 3] = excl + s2;
    if (t == 255) bsums[blockIdx.x] = val;   // block total
}

// scan the block sums (SCAN_NB <= 1024), in-place exclusive
__global__ __launch_bounds__(1024) void scan2_kernel(int* __restrict__ bsums) {
    __shared__ int lds[1024];
    int t = threadIdx.x;
    int v = (t < SCAN_NB) ? bsums[t] : 0;
    lds[t] = v;
    __syncthreads();
    int val = v;
    for (int off = 1; off < 1024; off <<= 1) {
        int y = (t >= off) ? lds[t - off] : 0;
        __syncthreads();
        val += y;
        lds[t] = val;
        __syncthreads();
    }
    if (t < SCAN_NB) bsums[t] = val - v;     // exclusive
}

// offsets = part + bsums[block]; cursor = same (cursor is consumed by bucketing)
__global__ __launch_bounds__(256) void scan3_kernel(
    const int* __restrict__ part, const int* __restrict__ bsums,
    int* __restrict__ offsets, int* __restrict__ cursor) {
    int t = threadIdx.x;
    int base = blockIdx.x * SCAN_BS + t * 4;
    int add = bsums[blockIdx.x];
#pragma unroll
    for (int i = 0; i < 4; ++i) {
        int idx = base + i;
        if (idx < RN) {
            int o = part[idx] + add;
            offsets[idx] = o;
            cursor[idx]  = o;
        }
    }
}

// scatter src ids into dst-sorted buckets; afterwards cursor[i] == segment end
__global__ __launch_bounds__(256) void bucket_kernel(
    const int* __restrict__ src, const int* __restrict__ dst,
    int* __restrict__ cursor, int* __restrict__ ebuf) {
    int e = blockIdx.x * 256 + threadIdx.x;
    if (e >= RE) return;
    int r = e / E_EDGES;
    int s = src[e];
    int pos = atomicAdd(&cursor[r * N_NODES + dst[e]], 1);
    ebuf[pos] = s;
}

// ---- pull-based aggregate -----------------------------------------------
// one wave per dst node: msg[node] = (1/max(deg,1)) * sum_{e in seg} x[src_e]
__global__ __launch_bounds__(256) void gather_kernel(
    const float* __restrict__ x,
    const int*   __restrict__ offsets,
    const int*   __restrict__ seg_end,   // cursor after bucketing == end
    const int*   __restrict__ ebuf,
    float* __restrict__ msg, int r) {
    int node = (blockIdx.x << 2) + (threadIdx.x >> 6);
    if (node >= N_NODES) return;
    int lane = threadIdx.x & 63;
    size_t base = (size_t)r * N_NODES + node;
    int beg = offsets[base];
    int end = seg_end[base];
    float accx = 0.f, accy = 0.f;
    int i = beg;
    for (; i + 1 < end; i += 2) {          // 2-deep unroll to overlap latency
        int s0 = ebuf[i];
        int s1 = ebuf[i + 1];
        float2 a = *(const float2*)(x + (size_t)s0 * D_FEAT + 2 * lane);
        float2 b = *(const float2*)(x + (size_t)s1 * D_FEAT + 2 * lane);
        accx += a.x + b.x;
        accy += a.y + b.y;
    }
    if (i < end) {
        int s = ebuf[i];
        float2 a = *(const float2*)(x + (size_t)s * D_FEAT + 2 * lane);
        accx += a.x;
        accy += a.y;
    }
    int d = end - beg;
    float inv = 1.0f / (float)(d > 1 ? d : 1);
    float2 o = make_float2(accx * inv, accy * inv);
    *(float2*)(msg + (size_t)node * D_FEAT + 2 * lane) = o;
}

// ---- GEMM ---------------------------------------------------------------
// C = maybe_relu( A @ W + addsrc + bias )   (or C += ... when accum)
__global__ __launch_bounds__(256) void gemm128_kernel(
    const float* __restrict__ A,
    const float* __restrict__ W,
    const float* __restrict__ addsrc,   // nullable
    const float* __restrict__ bias,     // nullable
    float* __restrict__ C,
    int M, int do_relu, int accum) {
    const int tid  = threadIdx.x;
    const int cg   = tid & 31;
    const int rg   = tid >> 5;
    const int col  = cg << 2;
    const int row0 = blockIdx.x * 64 + rg * 8;

    float4 acc[8];
#pragma unroll
    for (int i = 0; i < 8; ++i) acc[i] = make_float4(0.f, 0.f, 0.f, 0.f);

    const float* arow[8];
#pragma unroll
    for (int i = 0; i < 8; ++i) {
        int m = row0 + i;
        int mc = m < M ? m : M - 1;
        arow[i] = A + (size_t)mc * D_FEAT;
    }

    for (int k0 = 0; k0 < D_FEAT; k0 += 4) {
        float4 w0 = *(const float4*)(W + (k0 + 0) * D_FEAT + col);
        float4 w1 = *(const float4*)(W + (k0 + 1) * D_FEAT + col);
        float4 w2 = *(const float4*)(W + (k0 + 2) * D_FEAT + col);
        float4 w3 = *(const float4*)(W + (k0 + 3) * D_FEAT + col);
#pragma unroll
        for (int i = 0; i < 8; ++i) {
            float4 a = *(const float4*)(arow[i] + k0);
            acc[i].x = fmaf(a.x, w0.x, fmaf(a.y, w1.x, fmaf(a.z, w2.x, fmaf(a.w, w3.x, acc[i].x))));
            acc[i].y = fmaf(a.x, w0.y, fmaf(a.y, w1.y, fmaf(a.z, w2.y, fmaf(a.w, w3.y, acc[i].y))));
            acc[i].z = fmaf(a.x, w0.z, fmaf(a.y, w1.z, fmaf(a.z, w2.z, fmaf(a.w, w3.z, acc[i].z))));
            acc[i].w = fmaf(a.x, w0.w, fmaf(a.y, w1.w, fmaf(a.z, w2.w, fmaf(a.w, w3.w, acc[i].w))));
        }
    }

#pragma unroll
    for (int i = 0; i < 8; ++i) {
        int m = row0 + i;
        if (m < M) {
            float4 v = acc[i];
            if (addsrc) {
                float4 ad = *(const float4*)(addsrc + (size_t)m * D_FEAT + col);
                v.x += ad.x; v.y += ad.y; v.z += ad.z; v.w += ad.w;
            }
            if (bias) {
                float4 bs = *(const float4*)(bias + col);
                v.x += bs.x; v.y += bs.y; v.z += bs.z; v.w += bs.w;
            }
            if (accum) {
                float4 c = *(const float4*)(C + (size_t)m * D_FEAT + col);
                v.x += c.x; v.y += c.y; v.z += c.z; v.w += c.w;
            }
            if (do_relu) {
                v.x = fmaxf(v.x, 0.f); v.y = fmaxf(v.y, 0.f);
                v.z = fmaxf(v.z, 0.f); v.w = fmaxf(v.w, 0.f);
            }
            *(float4*)(C + (size_t)m * D_FEAT + col) = v;
        }
    }
}

extern "C" void kernel_launch(void* const* d_in, const int* in_sizes, int n_in,
                              void* d_out, int out_size, void* d_ws, size_t ws_size,
                              hipStream_t stream) {
    const float* x           = (const float*)d_in[0];
    const int*   edge_src    = (const int*)d_in[1];
    const int*   edge_dst    = (const int*)d_in[2];
    const float* w_comp      = (const float*)d_in[3];
    const float* bases       = (const float*)d_in[4];
    const float* loop_weight = (const float*)d_in[5];
    const float* h_bias      = (const float*)d_in[6];
    const float* ngnn_w      = (const float*)d_in[7];
    float* out = (float*)d_out;

    // workspace layout (~138 MB)
    char* ws = (char*)d_ws;
    size_t off = 0;
    float* weight  = (float*)(ws + off); off += (size_t)R_REL * D_FEAT * D_FEAT * 4;  // 512 KB
    float* msg     = (float*)(ws + off); off += (size_t)N_NODES * D_FEAT * 4;         // 51.2 MB
    float* h       = (float*)(ws + off); off += (size_t)N_NODES * D_FEAT * 4;         // 51.2 MB
    int*   deg     = (int*)  (ws + off); off += (size_t)RN * 4;                       // 3.2 MB
    int*   offsets = (int*)  (ws + off); off += (size_t)RN * 4;                       // 3.2 MB
    int*   cursor  = (int*)  (ws + off); off += (size_t)RN * 4;                       // 3.2 MB
    int*   ebuf    = (int*)  (ws + off); off += (size_t)RE * 4;                       // 25.6 MB
    int*   part    = (int*)  (ws + off); off += (size_t)RN * 4;                       // 3.2 MB
    int*   bsums   = (int*)  (ws + off); off += (size_t)SCAN_NB * 4;

    const int GEMM_GRID = (N_NODES + 63) / 64;   // 1563
    const size_t MAT_BYTES = (size_t)N_NODES * D_FEAT * 4;

    // 0) basis-combined weights, zero h accumulator + degree counters
    compute_weight_kernel<<<(R_REL * D_FEAT * D_FEAT + 255) / 256, 256, 0, stream>>>(
        w_comp, bases, weight);
    hipMemsetAsync(h, 0, MAT_BYTES, stream);
    hipMemsetAsync(deg, 0, (size_t)RN * 4, stream);

    // 1) CSR build: count -> scan -> bucket (cursor ends as segment end)
    count_kernel<<<(RE + 255) / 256, 256, 0, stream>>>(edge_dst, deg);
    scan1_kernel<<<SCAN_NB, 256, 0, stream>>>(deg, part, bsums);
    scan2_kernel<<<1, 1024, 0, stream>>>(bsums);
    scan3_kernel<<<SCAN_NB, 256, 0, stream>>>(part, bsums, offsets, cursor);
    bucket_kernel<<<(RE + 255) / 256, 256, 0, stream>>>(edge_src, edge_dst, cursor, ebuf);

    // 2) per-relation: pull-gather (normalized) then h += msg @ weight[r]
    for (int r = 0; r < R_REL; ++r) {
        gather_kernel<<<(N_NODES + 3) / 4, 256, 0, stream>>>(
            x, offsets, cursor, ebuf, msg, r);
        gemm128_kernel<<<GEMM_GRID, 256, 0, stream>>>(
            msg, weight + (size_t)r * D_FEAT * D_FEAT,
            nullptr, nullptr, h, N_NODES, /*relu=*/0, /*accum=*/1);
    }

    // 3) h2 = relu(x @ loop_weight + h + bias)   (h2 in msg buffer)
    gemm128_kernel<<<GEMM_GRID, 256, 0, stream>>>(
        x, loop_weight, h, h_bias, msg, N_NODES, /*relu=*/1, /*accum=*/0);

    // 4) h3 = relu(h2 @ ngnn_w[0])   (h3 in h buffer)
    gemm128_kernel<<<GEMM_GRID, 256, 0, stream>>>(
        msg, ngnn_w, nullptr, nullptr, h, N_NODES, /*relu=*/1, /*accum=*/0);

    // 5) out = relu(h3 @ ngnn_w[1])
    gemm128_kernel<<<GEMM_GRID, 256, 0, stream>>>(
        h, ngnn_w + D_FEAT * D_FEAT, nullptr, nullptr, out, N_NODES, /*relu=*/1, /*accum=*/0);
}

// Round 3
// 1760.737 us; speedup vs baseline: 6.9635x; 1.2668x over previous
//
#include <hip/hip_runtime.h>
#include <hip/hip_bf16.h>

#define N_NODES 100000
#define R_REL   8
#define E_EDGES 800000
#define D_FEAT  128
#define B_BASES 4
#define RN      (R_REL * N_NODES)          // 800000 keys (key = dst*8 + r)
#define RE      (R_REL * E_EDGES)          // 6.4M edges
#define SCAN_BS 1024
#define SCAN_NB ((RN + SCAN_BS - 1) / SCAN_BS)   // 782

// ---- CSR build (key = dst*8 + r, so a node's 8 segments are contiguous) ----

__global__ __launch_bounds__(256) void count_kernel(
    const int* __restrict__ dst, int* __restrict__ deg) {
    int e = blockIdx.x * 256 + threadIdx.x;
    if (e >= RE) return;
    int r = e / E_EDGES;
    atomicAdd(&deg[dst[e] * R_REL + r], 1);
}

__global__ __launch_bounds__(256) void scan1_kernel(
    const int* __restrict__ deg, int* __restrict__ part, int* __restrict__ bsums) {
    __shared__ int lds[256];
    int t = threadIdx.x;
    int base = blockIdx.x * SCAN_BS + t * 4;
    int v0 = base + 0 < RN ? deg[base + 0] : 0;
    int v1 = base + 1 < RN ? deg[base + 1] : 0;
    int v2 = base + 2 < RN ? deg[base + 2] : 0;
    int v3 = base + 3 < RN ? deg[base + 3] : 0;
    int s0 = v0, s1 = s0 + v1, s2 = s1 + v2, s3 = s2 + v3;
    lds[t] = s3;
    __syncthreads();
    int val = s3;
    for (int off = 1; off < 256; off <<= 1) {
        int y = (t >= off) ? lds[t - off] : 0;
        __syncthreads();
        val += y;
        lds[t] = val;
        __syncthreads();
    }
    int excl = val - s3;
    if (base + 0 < RN) part[base + 0] = excl;
    if (base + 1 < RN) part[base + 1] = excl + s0;
    if (base + 2 < RN) part[base + 2] = excl + s1;
    if (base + 3 < RN) part[base + 3] = excl + s2;
    if (t == 255) bsums[blockIdx.x] = val;
}

__global__ __launch_bounds__(1024) void scan2_kernel(int* __restrict__ bsums) {
    __shared__ int lds[1024];
    int t = threadIdx.x;
    int v = (t < SCAN_NB) ? bsums[t] : 0;
    lds[t] = v;
    __syncthreads();
    int val = v;
    for (int off = 1; off < 1024; off <<= 1) {
        int y = (t >= off) ? lds[t - off] : 0;
        __syncthreads();
        val += y;
        lds[t] = val;
        __syncthreads();
    }
    if (t < SCAN_NB) bsums[t] = val - v;
}

__global__ __launch_bounds__(256) void scan3_kernel(
    const int* __restrict__ part, const int* __restrict__ bsums,
    int* __restrict__ offsets, int* __restrict__ cursor) {
    int t = threadIdx.x;
    int base = blockIdx.x * SCAN_BS + t * 4;
    int add = bsums[blockIdx.x];
#pragma unroll
    for (int i = 0; i < 4; ++i) {
        int idx = base + i;
        if (idx < RN) {
            int o = part[idx] + add;
            offsets[idx] = o;
            cursor[idx]  = o;
        }
    }
    if (base == 0 && blockIdx.x == 0) offsets[RN] = RE;   // sentinel end
}

__global__ __launch_bounds__(256) void bucket_kernel(
    const int* __restrict__ src, const int* __restrict__ dst,
    int* __restrict__ cursor, int* __restrict__ ebuf) {
    int e = blockIdx.x * 256 + threadIdx.x;
    if (e >= RE) return;
    int r = e / E_EDGES;
    int pos = atomicAdd(&cursor[dst[e] * R_REL + r], 1);
    ebuf[pos] = src[e];
}

// ---- fused gather: all 8 relations -> 4 basis-combined bf16 outputs -------
// one wave per node; lane holds feats {2*lane, 2*lane+1}
// y[n][b*128 + f] = sum_r w_comp[r][b]/max(deg_{r,n},1) * sum_{e in seg(n,r)} x[src_e][f]
__global__ __launch_bounds__(256) void gather_kernel(
    const float* __restrict__ x,
    const int*   __restrict__ offsets,
    const int*   __restrict__ ebuf,
    const float* __restrict__ w_comp,
    __hip_bfloat162* __restrict__ y) {     // [N][256] bf162
    int node = (blockIdx.x << 2) + (threadIdx.x >> 6);
    if (node >= N_NODES) return;
    int lane = threadIdx.x & 63;
    const float* xp = x + 2 * lane;

    float2 acc[R_REL];
    float  inv[R_REL];
    int segbase = node * R_REL;
#pragma unroll
    for (int r = 0; r < R_REL; ++r) {
        int beg = offsets[segbase + r];
        int end = offsets[segbase + r + 1];
        int d = end - beg;
        inv[r] = 1.0f / (float)(d > 1 ? d : 1);
        float ax = 0.f, ay = 0.f;
        int i = beg;
        for (; i + 3 < end; i += 4) {           // 4-deep for MLP ILP
            int s0 = ebuf[i], s1 = ebuf[i + 1], s2 = ebuf[i + 2], s3 = ebuf[i + 3];
            float2 a = *(const float2*)(xp + (size_t)s0 * D_FEAT);
            float2 b = *(const float2*)(xp + (size_t)s1 * D_FEAT);
            float2 c = *(const float2*)(xp + (size_t)s2 * D_FEAT);
            float2 d2 = *(const float2*)(xp + (size_t)s3 * D_FEAT);
            ax += (a.x + b.x) + (c.x + d2.x);
            ay += (a.y + b.y) + (c.y + d2.y);
        }
        for (; i < end; ++i) {
            int s = ebuf[i];
            float2 a = *(const float2*)(xp + (size_t)s * D_FEAT);
            ax += a.x; ay += a.y;
        }
        acc[r] = make_float2(ax, ay);
    }

#pragma unroll
    for (int b = 0; b < B_BASES; ++b) {
        float sx = 0.f, sy = 0.f;
#pragma unroll
        for (int r = 0; r < R_REL; ++r) {
            float coef = w_comp[r * B_BASES + b] * inv[r];
            sx = fmaf(coef, acc[r].x, sx);
            sy = fmaf(coef, acc[r].y, sy);
        }
        y[(size_t)node * 256 + b * 64 + lane] = __float22bfloat162_rn(make_float2(sx, sy));
    }
}

// ---- big GEMM: out = relu([y(bf16) | x] @ [bases ; loop_weight] + bias) ---
// K = 512 (y, bf16) + 128 (x, fp32). 64 rows/block, thread = 8 rows x 4 cols.
__global__ __launch_bounds__(256) void gemm_big_kernel(
    const uint* __restrict__ y,            // [N][256] packed bf16 pairs
    const float* __restrict__ x,
    const float* __restrict__ bases,       // [512][128] stacked
    const float* __restrict__ loopw,       // [128][128]
    const float* __restrict__ bias,
    float* __restrict__ C) {
    const int tid  = threadIdx.x;
    const int cg   = tid & 31;
    const int rg   = tid >> 5;
    const int col  = cg << 2;
    const int row0 = blockIdx.x * 64 + rg * 8;

    float4 acc[8];
#pragma unroll
    for (int i = 0; i < 8; ++i) acc[i] = make_float4(0.f, 0.f, 0.f, 0.f);

    int rowc[8];
#pragma unroll
    for (int i = 0; i < 8; ++i) {
        int m = row0 + i;
        rowc[i] = m < N_NODES ? m : N_NODES - 1;
    }

    // phase 1: K=512 from bf16 y
    for (int k0 = 0; k0 < 512; k0 += 4) {
        float4 w0 = *(const float4*)(bases + (k0 + 0) * D_FEAT + col);
        float4 w1 = *(const float4*)(bases + (k0 + 1) * D_FEAT + col);
        float4 w2 = *(const float4*)(bases + (k0 + 2) * D_FEAT + col);
        float4 w3 = *(const float4*)(bases + (k0 + 3) * D_FEAT + col);
#pragma unroll
        for (int i = 0; i < 8; ++i) {
            uint2 u = *(const uint2*)(y + (size_t)rowc[i] * 256 + (k0 >> 1));
            float a0 = __uint_as_float(u.x << 16);
            float a1 = __uint_as_float(u.x & 0xFFFF0000u);
            float a2 = __uint_as_float(u.y << 16);
            float a3 = __uint_as_float(u.y & 0xFFFF0000u);
            acc[i].x = fmaf(a0, w0.x, fmaf(a1, w1.x, fmaf(a2, w2.x, fmaf(a3, w3.x, acc[i].x))));
            acc[i].y = fmaf(a0, w0.y, fmaf(a1, w1.y, fmaf(a2, w2.y, fmaf(a3, w3.y, acc[i].y))));
            acc[i].z = fmaf(a0, w0.z, fmaf(a1, w1.z, fmaf(a2, w2.z, fmaf(a3, w3.z, acc[i].z))));
            acc[i].w = fmaf(a0, w0.w, fmaf(a1, w1.w, fmaf(a2, w2.w, fmaf(a3, w3.w, acc[i].w))));
        }
    }
    // phase 2: K=128 from fp32 x (self loop)
    for (int k0 = 0; k0 < 128; k0 += 4) {
        float4 w0 = *(const float4*)(loopw + (k0 + 0) * D_FEAT + col);
        float4 w1 = *(const float4*)(loopw + (k0 + 1) * D_FEAT + col);
        float4 w2 = *(const float4*)(loopw + (k0 + 2) * D_FEAT + col);
        float4 w3 = *(const float4*)(loopw + (k0 + 3) * D_FEAT + col);
#pragma unroll
        for (int i = 0; i < 8; ++i) {
            float4 a = *(const float4*)(x + (size_t)rowc[i] * D_FEAT + k0);
            acc[i].x = fmaf(a.x, w0.x, fmaf(a.y, w1.x, fmaf(a.z, w2.x, fmaf(a.w, w3.x, acc[i].x))));
            acc[i].y = fmaf(a.x, w0.y, fmaf(a.y, w1.y, fmaf(a.z, w2.y, fmaf(a.w, w3.y, acc[i].y))));
            acc[i].z = fmaf(a.x, w0.z, fmaf(a.y, w1.z, fmaf(a.z, w2.z, fmaf(a.w, w3.z, acc[i].z))));
            acc[i].w = fmaf(a.x, w0.w, fmaf(a.y, w1.w, fmaf(a.z, w2.w, fmaf(a.w, w3.w, acc[i].w))));
        }
    }

    float4 bs = *(const float4*)(bias + col);
#pragma unroll
    for (int i = 0; i < 8; ++i) {
        int m = row0 + i;
        if (m < N_NODES) {
            float4 v = acc[i];
            v.x = fmaxf(v.x + bs.x, 0.f);
            v.y = fmaxf(v.y + bs.y, 0.f);
            v.z = fmaxf(v.z + bs.z, 0.f);
            v.w = fmaxf(v.w + bs.w, 0.f);
            *(float4*)(C + (size_t)m * D_FEAT + col) = v;
        }
    }
}

// ---- fp32 128x128 GEMM, C = relu(A @ W), safe for C == A (in-place) ------
__global__ __launch_bounds__(256) void gemm128_kernel(
    const float* __restrict__ A,
    const float* __restrict__ W,
    float* __restrict__ C, int M) {
    const int tid  = threadIdx.x;
    const int cg   = tid & 31;
    const int rg   = tid >> 5;
    const int col  = cg << 2;
    const int row0 = blockIdx.x * 64 + rg * 8;

    float4 acc[8];
#pragma unroll
    for (int i = 0; i < 8; ++i) acc[i] = make_float4(0.f, 0.f, 0.f, 0.f);

    const float* arow[8];
#pragma unroll
    for (int i = 0; i < 8; ++i) {
        int m = row0 + i;
        arow[i] = A + (size_t)(m < M ? m : M - 1) * D_FEAT;
    }

    for (int k0 = 0; k0 < D_FEAT; k0 += 4) {
        float4 w0 = *(const float4*)(W + (k0 + 0) * D_FEAT + col);
        float4 w1 = *(const float4*)(W + (k0 + 1) * D_FEAT + col);
        float4 w2 = *(const float4*)(W + (k0 + 2) * D_FEAT + col);
        float4 w3 = *(const float4*)(W + (k0 + 3) * D_FEAT + col);
#pragma unroll
        for (int i = 0; i < 8; ++i) {
            float4 a = *(const float4*)(arow[i] + k0);
            acc[i].x = fmaf(a.x, w0.x, fmaf(a.y, w1.x, fmaf(a.z, w2.x, fmaf(a.w, w3.x, acc[i].x))));
            acc[i].y = fmaf(a.x, w0.y, fmaf(a.y, w1.y, fmaf(a.z, w2.y, fmaf(a.w, w3.y, acc[i].y))));
            acc[i].z = fmaf(a.x, w0.z, fmaf(a.y, w1.z, fmaf(a.z, w2.z, fmaf(a.w, w3.z, acc[i].z))));
            acc[i].w = fmaf(a.x, w0.w, fmaf(a.y, w1.w, fmaf(a.z, w2.w, fmaf(a.w, w3.w, acc[i].w))));
        }
    }

    __syncthreads();   // in-place safety: all A reads complete before any store
#pragma unroll
    for (int i = 0; i < 8; ++i) {
        int m = row0 + i;
        if (m < M) {
            float4 v = acc[i];
            v.x = fmaxf(v.x, 0.f); v.y = fmaxf(v.y, 0.f);
            v.z = fmaxf(v.z, 0.f); v.w = fmaxf(v.w, 0.f);
            *(float4*)(C + (size_t)m * D_FEAT + col) = v;
        }
    }
}

extern "C" void kernel_launch(void* const* d_in, const int* in_sizes, int n_in,
                              void* d_out, int out_size, void* d_ws, size_t ws_size,
                              hipStream_t stream) {
    const float* x           = (const float*)d_in[0];
    const int*   edge_src    = (const int*)d_in[1];
    const int*   edge_dst    = (const int*)d_in[2];
    const float* w_comp      = (const float*)d_in[3];
    const float* bases       = (const float*)d_in[4];
    const float* loop_weight = (const float*)d_in[5];
    const float* h_bias      = (const float*)d_in[6];
    const float* ngnn_w      = (const float*)d_in[7];
    float* out = (float*)d_out;

    // workspace layout (~141 MB)
    char* ws = (char*)d_ws;
    size_t off = 0;
    __hip_bfloat162* y = (__hip_bfloat162*)(ws + off); off += (size_t)N_NODES * 512 * 2; // 102.4 MB
    int* ebuf    = (int*)(ws + off); off += (size_t)RE * 4;                              // 25.6 MB
    int* offsets = (int*)(ws + off); off += ((size_t)RN + 1) * 4;                        // 3.2 MB
    int* cursor  = (int*)(ws + off); off += (size_t)RN * 4;                              // 3.2 MB
    int* deg     = (int*)(ws + off); off += (size_t)RN * 4;                              // 3.2 MB
    int* part    = (int*)(ws + off); off += (size_t)RN * 4;                              // 3.2 MB
    int* bsums   = (int*)(ws + off); off += (size_t)SCAN_NB * 4;

    const int GEMM_GRID = (N_NODES + 63) / 64;   // 1563

    // 1) CSR build
    hipMemsetAsync(deg, 0, (size_t)RN * 4, stream);
    count_kernel<<<(RE + 255) / 256, 256, 0, stream>>>(edge_dst, deg);
    scan1_kernel<<<SCAN_NB, 256, 0, stream>>>(deg, part, bsums);
    scan2_kernel<<<1, 1024, 0, stream>>>(bsums);
    scan3_kernel<<<SCAN_NB, 256, 0, stream>>>(part, bsums, offsets, cursor);
    bucket_kernel<<<(RE + 255) / 256, 256, 0, stream>>>(edge_src, edge_dst, cursor, ebuf);

    // 2) fused gather -> y (bf16, basis-combined)
    gather_kernel<<<(N_NODES + 3) / 4, 256, 0, stream>>>(x, offsets, ebuf, w_comp, y);

    // 3) out = relu([y|x] @ [bases;loop_w] + bias)
    gemm_big_kernel<<<GEMM_GRID, 256, 0, stream>>>(
        (const uint*)y, x, bases, loop_weight, h_bias, out);

    // 4) NGNN in-place on d_out
    gemm128_kernel<<<GEMM_GRID, 256, 0, stream>>>(out, ngnn_w, out, N_NODES);
    gemm128_kernel<<<GEMM_GRID, 256, 0, stream>>>(out, ngnn_w + D_FEAT * D_FEAT, out, N_NODES);
}